// Round 9
// baseline (6710.033 us; speedup 1.0000x reference)
//
#include <hip/hip_runtime.h>
#include <hip/hip_bf16.h>

#define NN 50000
#define EE 1200000
#define GG 256
#define LL 5

// fast silu
__device__ __forceinline__ float silu_f(float x) {
    return x * __builtin_amdgcn_rcpf(1.0f + __expf(-x));
}
__device__ __forceinline__ int rfl(int x) { return __builtin_amdgcn_readfirstlane(x); }

// ---------- CSR build ----------
__global__ __launch_bounds__(256) void k_hist(const int* __restrict__ ei, int* __restrict__ fill, int E) {
    int e = blockIdx.x * 256 + threadIdx.x;
    if (e < E) atomicAdd(&fill[ei[E + e]], 1);
}

__global__ __launch_bounds__(1024) void k_scan(const int* __restrict__ cnt, int* __restrict__ rowptr,
                                               float* __restrict__ degf, int* __restrict__ fill, int n) {
    __shared__ int wsum[16];
    __shared__ int carry_s;
    int tid = threadIdx.x, lane = tid & 63, wid = tid >> 6;
    if (tid == 0) carry_s = 0;
    __syncthreads();
    for (int base = 0; base < n; base += 1024) {
        int i = base + tid;
        int v = (i < n) ? cnt[i] : 0;
        int x = v;
        #pragma unroll
        for (int off = 1; off < 64; off <<= 1) {
            int t = __shfl_up(x, off);
            if (lane >= off) x += t;
        }
        if (lane == 63) wsum[wid] = x;
        __syncthreads();
        if (wid == 0 && lane < 16) {
            int w = wsum[lane];
            #pragma unroll
            for (int off = 1; off < 16; off <<= 1) {
                int t = __shfl_up(w, off);
                if (lane >= off) w += t;
            }
            wsum[lane] = w;
        }
        __syncthreads();
        int waveoff = (wid == 0) ? 0 : wsum[wid - 1];
        int inc = x + waveoff;
        int c = carry_s;
        int chunk_total = wsum[15];
        __syncthreads();
        if (i < n) {
            rowptr[i + 1] = c + inc;
            degf[i] = (float)(v > 0 ? v : 1);
            fill[i] = 0;
        }
        if (tid == 0) {
            if (base == 0) rowptr[0] = 0;
            carry_s = c + chunk_total;
        }
        __syncthreads();
    }
}

// packed scatter: ONE 4B write per edge. v = (ea15 << 17) | src
__global__ __launch_bounds__(256) void k_scatter(const int* __restrict__ ei, const float* __restrict__ ea,
                                                 const int* __restrict__ rowptr, int* __restrict__ fill,
                                                 unsigned int* __restrict__ edata, int E) {
    int e = blockIdx.x * 256 + threadIdx.x;
    if (e < E) {
        int d = ei[E + e];
        int pos = atomicAdd(&fill[d], 1);
        int idx = rowptr[d] + pos;
        int ea15 = (int)(ea[e] * 32768.0f + 0.5f);
        if (ea15 > 32767) ea15 = 32767;
        edata[idx] = ((unsigned int)ea15 << 17) | (unsigned int)ei[e];
    }
}

// ---------- weight fold ----------
__global__ __launch_bounds__(256) void k_fold(const float* __restrict__ msg_W2, const float* __restrict__ msg_b2,
                                              const float* __restrict__ upd_W, float* __restrict__ W2p,
                                              float* __restrict__ b2p) {
    int l = blockIdx.x;
    const float* W2 = msg_W2 + (size_t)l * 4096;
    const float* U2 = upd_W + (size_t)l * 8192 + 4096;
    int lane = threadIdx.x & 63, wid = threadIdx.x >> 6;
    for (int ii = 0; ii < 16; ii++) {
        int i = rfl(wid * 16 + ii);
        float acc = 0.0f;
        for (int k = 0; k < 64; k++) acc = fmaf(W2[i * 64 + k], U2[k * 64 + lane], acc);
        W2p[(size_t)l * 4096 + i * 64 + lane] = acc;
    }
    if (wid == 0) {
        float acc = 0.0f;
        for (int k = 0; k < 64; k++) acc = fmaf(msg_b2[l * 64 + k], U2[k * 64 + lane], acc);
        b2p[l * 64 + lane] = acc;
    }
}

// ---------- node embedding: LDS-staged x tile (64 rows), k-step 8, VGPR-capped ----------
__global__ __launch_bounds__(256, 3) void k_node_emb(const float* __restrict__ x, const float* __restrict__ W,
                                                     const float* __restrict__ b, float* __restrict__ h, int n) {
    __shared__ float sW[5888];   // 92*64
    __shared__ float xt[5888];   // 64 rows * 92
    int tid = threadIdx.x;
    for (int i = tid; i < 5888; i += 256) sW[i] = W[i];
    int rb = blockIdx.x << 6;
    int valid = n - rb; if (valid > 64) valid = 64;
    {
        const float4* g4 = (const float4*)(x + (size_t)rb * 92);
        float4* x4 = (float4*)xt;
        int cnt4 = valid * 23;   // 92/4
        for (int i = tid; i < cnt4; i += 256) x4[i] = g4[i];
    }
    __syncthreads();
    int lane = tid & 63, wid = tid >> 6;
    float bj = b[lane];
    #pragma unroll
    for (int g8 = 0; g8 < 2; g8++) {
        int r0 = (wid << 4) + (g8 << 3);
        if (rb + r0 >= n) continue;
        float acc[8];
        #pragma unroll
        for (int r = 0; r < 8; r++) acc[r] = bj;
        for (int kb = 0; kb < 88; kb += 8) {
            float wv[8];
            #pragma unroll
            for (int t = 0; t < 8; t++) wv[t] = sW[(kb + t) * 64 + lane];
            #pragma unroll
            for (int r = 0; r < 8; r++) {
                const float4* xr = (const float4*)&xt[(r0 + r) * 92 + kb];
                float4 v0 = xr[0], v1 = xr[1];
                acc[r] = fmaf(v0.x, wv[0], acc[r]);
                acc[r] = fmaf(v0.y, wv[1], acc[r]);
                acc[r] = fmaf(v0.z, wv[2], acc[r]);
                acc[r] = fmaf(v0.w, wv[3], acc[r]);
                acc[r] = fmaf(v1.x, wv[4], acc[r]);
                acc[r] = fmaf(v1.y, wv[5], acc[r]);
                acc[r] = fmaf(v1.z, wv[6], acc[r]);
                acc[r] = fmaf(v1.w, wv[7], acc[r]);
            }
        }
        {   // tail k = 88..91
            float wv[4];
            #pragma unroll
            for (int t = 0; t < 4; t++) wv[t] = sW[(88 + t) * 64 + lane];
            #pragma unroll
            for (int r = 0; r < 8; r++) {
                const float4* xr = (const float4*)&xt[(r0 + r) * 92 + 88];
                float4 v = xr[0];
                acc[r] = fmaf(v.x, wv[0], acc[r]);
                acc[r] = fmaf(v.y, wv[1], acc[r]);
                acc[r] = fmaf(v.z, wv[2], acc[r]);
                acc[r] = fmaf(v.w, wv[3], acc[r]);
            }
        }
        #pragma unroll
        for (int r = 0; r < 8; r++) {
            int grow = rb + r0 + r;
            if (grow < n) h[(size_t)grow * 64 + lane] = acc[r];
        }
    }
}

// ---------- per-layer pre: src (raw h0 or u+BN) -> Hd fp32, Hs fp16. 64-row tile, k-step 8 ----------
__global__ __launch_bounds__(256, 3) void k_node_pre(const float* src, int bn,
        const float* __restrict__ bnsum, const float* __restrict__ bnsq,
        const float* __restrict__ bng, const float* __restrict__ bnbe, float invN,
        const float* __restrict__ W1, const float* __restrict__ b1,
        float* __restrict__ Hd, _Float16* __restrict__ Hs, int n) {
    __shared__ float sA[4096], sB[4096], xt[4096];
    __shared__ float ssc[64], ssh[64];
    int tid = threadIdx.x;
    if (tid < 64) {
        float sc = 1.0f, sh = 0.0f;
        if (bn) {
            float mean = bnsum[tid] * invN;
            float var = bnsq[tid] * invN - mean * mean;
            float inv = rsqrtf(var + 1e-5f);
            sc = inv * bng[tid];
            sh = fmaf(-mean, sc, bnbe[tid]);
        }
        ssc[tid] = sc; ssh[tid] = sh;
    }
    for (int i = tid; i < 4096; i += 256) { sA[i] = W1[i]; sB[i] = W1[4096 + i]; }
    __syncthreads();
    int rb = blockIdx.x << 6;
    int valid = n - rb; if (valid > 64) valid = 64;
    {
        const float4* g4 = (const float4*)(src + (size_t)rb * 64);
        float4* x4 = (float4*)xt;
        int cnt4 = valid << 4;
        for (int i = tid; i < cnt4; i += 256) {
            float4 v = g4[i];
            if (bn) {
                int c = (i & 15) << 2;
                v.x = silu_f(fmaf(v.x, ssc[c],     ssh[c]));
                v.y = silu_f(fmaf(v.y, ssc[c + 1], ssh[c + 1]));
                v.z = silu_f(fmaf(v.z, ssc[c + 2], ssh[c + 2]));
                v.w = silu_f(fmaf(v.w, ssc[c + 3], ssh[c + 3]));
            }
            x4[i] = v;
        }
    }
    __syncthreads();
    int lane = tid & 63, wid = tid >> 6;
    float bj = b1[lane];
    #pragma unroll
    for (int g8 = 0; g8 < 2; g8++) {
        int r0 = (wid << 4) + (g8 << 3);
        if (rb + r0 >= n) continue;
        float accA[8], accB[8];
        #pragma unroll
        for (int r = 0; r < 8; r++) { accA[r] = bj; accB[r] = 0.0f; }
        #pragma unroll
        for (int kb = 0; kb < 64; kb += 8) {
            float wA[8], wB[8];
            #pragma unroll
            for (int t = 0; t < 8; t++) { wA[t] = sA[(kb + t) * 64 + lane]; wB[t] = sB[(kb + t) * 64 + lane]; }
            #pragma unroll
            for (int r = 0; r < 8; r++) {
                const float4* xr = (const float4*)&xt[(r0 + r) * 64 + kb];
                float4 v0 = xr[0], v1 = xr[1];
                accA[r] = fmaf(v0.x, wA[0], accA[r]); accB[r] = fmaf(v0.x, wB[0], accB[r]);
                accA[r] = fmaf(v0.y, wA[1], accA[r]); accB[r] = fmaf(v0.y, wB[1], accB[r]);
                accA[r] = fmaf(v0.z, wA[2], accA[r]); accB[r] = fmaf(v0.z, wB[2], accB[r]);
                accA[r] = fmaf(v0.w, wA[3], accA[r]); accB[r] = fmaf(v0.w, wB[3], accB[r]);
                accA[r] = fmaf(v1.x, wA[4], accA[r]); accB[r] = fmaf(v1.x, wB[4], accB[r]);
                accA[r] = fmaf(v1.y, wA[5], accA[r]); accB[r] = fmaf(v1.y, wB[5], accB[r]);
                accA[r] = fmaf(v1.z, wA[6], accA[r]); accB[r] = fmaf(v1.z, wB[6], accB[r]);
                accA[r] = fmaf(v1.w, wA[7], accA[r]); accB[r] = fmaf(v1.w, wB[7], accB[r]);
            }
        }
        #pragma unroll
        for (int r = 0; r < 8; r++) {
            int grow = rb + r0 + r;
            if (grow < n) {
                Hd[(size_t)grow * 64 + lane] = accA[r];
                Hs[(size_t)grow * 64 + lane] = (_Float16)accB[r];
            }
        }
    }
}

// ---------- edge pass 1: sum(z), sum(z^2); fp16 gathers, 4B packed edata ----------
__global__ __launch_bounds__(256) void k_edge_stats(const float* __restrict__ Hd, const _Float16* __restrict__ Hs,
                                                    const int* __restrict__ rowptr, const unsigned int* __restrict__ edata,
                                                    const float* __restrict__ w1e,
                                                    float* __restrict__ esum, float* __restrict__ esq, int n) {
    __shared__ float rs[4][64], rq[4][64];
    int wid = threadIdx.x >> 6, lane = threadIdx.x & 63;
    int gw = (blockIdx.x * 256 + threadIdx.x) >> 6;
    int nw = (gridDim.x * 256) >> 6;
    float wj = w1e[lane] * (1.0f / 32768.0f);
    float s = 0.0f, q = 0.0f;
    for (int node = gw; node < n; node += nw) {
        int nu = rfl(node);
        int e0 = rowptr[nu], e1 = rowptr[nu + 1];
        if (e0 == e1) continue;
        float hd = Hd[(size_t)nu * 64 + lane];
        int e = e0;
        for (; e + 8 <= e1; e += 8) {
            float hs[8], av[8];
            #pragma unroll
            for (int j = 0; j < 8; j++) {
                unsigned int p = edata[e + j];
                int sidx = rfl((int)(p & 0x1FFFFu));
                av[j] = (float)rfl((int)(p >> 17));
                hs[j] = (float)Hs[(size_t)sidx * 64 + lane];
            }
            #pragma unroll
            for (int j = 0; j < 8; j++) {
                float z = fmaf(av[j], wj, hd) + hs[j];
                s += z;
                q = fmaf(z, z, q);
            }
        }
        for (; e < e1; e++) {
            unsigned int p = edata[e];
            int sidx = rfl((int)(p & 0x1FFFFu));
            float a = (float)rfl((int)(p >> 17));
            float z = fmaf(a, wj, hd) + (float)Hs[(size_t)sidx * 64 + lane];
            s += z;
            q = fmaf(z, z, q);
        }
    }
    rs[wid][lane] = s; rq[wid][lane] = q;
    __syncthreads();
    if (wid == 0) {
        float ts = rs[0][lane] + rs[1][lane] + rs[2][lane] + rs[3][lane];
        float tq = rq[0][lane] + rq[1][lane] + rq[2][lane] + rq[3][lane];
        atomicAdd(&esum[lane], ts);
        atomicAdd(&esq[lane], tq);
    }
}

// ---------- edge pass 2: sacc = (sum_in silu(bn(z)))/deg; fp16 gathers ----------
__global__ __launch_bounds__(256) void k_edge_agg(const float* __restrict__ Hd, const _Float16* __restrict__ Hs,
                                                  const int* __restrict__ rowptr, const unsigned int* __restrict__ edata,
                                                  const float* __restrict__ w1e,
                                                  const float* __restrict__ esum, const float* __restrict__ esq,
                                                  const float* __restrict__ g1, const float* __restrict__ be1,
                                                  const float* __restrict__ degf, float* __restrict__ sacc,
                                                  int n, float invE) {
    int lane = threadIdx.x & 63;
    float mean = esum[lane] * invE;
    float var = esq[lane] * invE - mean * mean;
    float inv = rsqrtf(var + 1e-5f);
    float sc = inv * g1[lane];
    float sh = fmaf(-mean, sc, be1[lane]);
    float wj = w1e[lane] * (1.0f / 32768.0f);
    int gw = (blockIdx.x * 256 + threadIdx.x) >> 6;
    int nw = (gridDim.x * 256) >> 6;
    for (int node = gw; node < n; node += nw) {
        int nu = rfl(node);
        int e0 = rowptr[nu], e1 = rowptr[nu + 1];
        float acc = 0.0f;
        float hd = Hd[(size_t)nu * 64 + lane];
        int e = e0;
        for (; e + 8 <= e1; e += 8) {
            float hs[8], av[8];
            #pragma unroll
            for (int j = 0; j < 8; j++) {
                unsigned int p = edata[e + j];
                int sidx = rfl((int)(p & 0x1FFFFu));
                av[j] = (float)rfl((int)(p >> 17));
                hs[j] = (float)Hs[(size_t)sidx * 64 + lane];
            }
            #pragma unroll
            for (int j = 0; j < 8; j++) {
                float z = fmaf(av[j], wj, hd) + hs[j];
                acc += silu_f(fmaf(z, sc, sh));
            }
        }
        for (; e < e1; e++) {
            unsigned int p = edata[e];
            int sidx = rfl((int)(p & 0x1FFFFu));
            float a = (float)rfl((int)(p >> 17));
            float z = fmaf(a, wj, hd) + (float)Hs[(size_t)sidx * 64 + lane];
            acc += silu_f(fmaf(z, sc, sh));
        }
        sacc[(size_t)nu * 64 + lane] = acc / degf[nu];
    }
}

// ---------- node update: u = stage(src,BN)@U1 + sacc@W2p + gate*b2p + ub ; stats. 32-row tile, k-step 8 ----------
__global__ __launch_bounds__(256, 3) void k_node_upd(const float* src, int bn,
        const float* __restrict__ bnsum, const float* __restrict__ bnsq,
        const float* __restrict__ bng, const float* __restrict__ bnbe, float invN,
        const float* __restrict__ sacc,
        const float* __restrict__ U1, const float* __restrict__ W2p,
        const float* __restrict__ b2p, const float* __restrict__ ub,
        const int* __restrict__ rowptr, float* u,
        float* __restrict__ usum, float* __restrict__ usq, int n) {
    __shared__ float sU[4096], sP[4096], ht[2048], st[2048];
    __shared__ float ssc[64], ssh[64];
    __shared__ float rs[4][64], rq[4][64];
    int tid = threadIdx.x;
    if (tid < 64) {
        float sc = 1.0f, sh = 0.0f;
        if (bn) {
            float mean = bnsum[tid] * invN;
            float var = bnsq[tid] * invN - mean * mean;
            float inv = rsqrtf(var + 1e-5f);
            sc = inv * bng[tid];
            sh = fmaf(-mean, sc, bnbe[tid]);
        }
        ssc[tid] = sc; ssh[tid] = sh;
    }
    for (int i = tid; i < 4096; i += 256) { sU[i] = U1[i]; sP[i] = W2p[i]; }
    __syncthreads();
    int rb = blockIdx.x << 5;
    int valid = n - rb; if (valid > 32) valid = 32;
    {
        const float4* g4 = (const float4*)(src + (size_t)rb * 64);
        const float4* s4 = (const float4*)(sacc + (size_t)rb * 64);
        float4* h4 = (float4*)ht;
        float4* t4 = (float4*)st;
        int cnt4 = valid << 4;
        for (int i = tid; i < cnt4; i += 256) {
            float4 v = g4[i];
            if (bn) {
                int c = (i & 15) << 2;
                v.x = silu_f(fmaf(v.x, ssc[c],     ssh[c]));
                v.y = silu_f(fmaf(v.y, ssc[c + 1], ssh[c + 1]));
                v.z = silu_f(fmaf(v.z, ssc[c + 2], ssh[c + 2]));
                v.w = silu_f(fmaf(v.w, ssc[c + 3], ssh[c + 3]));
            }
            h4[i] = v;
            t4[i] = s4[i];
        }
    }
    __syncthreads();
    int lane = tid & 63, wid = tid >> 6;
    float b2j = b2p[lane], ubj = ub[lane];
    float s = 0.0f, q = 0.0f;
    int r0 = wid << 3;
    if (rb + r0 < n) {
        float acc[8];
        #pragma unroll
        for (int r = 0; r < 8; r++) {
            int grow = rb + r0 + r;
            if (grow < n) {
                int c0 = rowptr[grow], c1 = rowptr[grow + 1];
                acc[r] = ubj + (c1 > c0 ? b2j : 0.0f);
            } else acc[r] = 0.0f;
        }
        #pragma unroll
        for (int kb = 0; kb < 64; kb += 8) {
            float wU[8], wP[8];
            #pragma unroll
            for (int t = 0; t < 8; t++) { wU[t] = sU[(kb + t) * 64 + lane]; wP[t] = sP[(kb + t) * 64 + lane]; }
            #pragma unroll
            for (int r = 0; r < 8; r++) {
                const float4* hr = (const float4*)&ht[(r0 + r) * 64 + kb];
                const float4* sr = (const float4*)&st[(r0 + r) * 64 + kb];
                float4 h0v = hr[0], h1v = hr[1];
                float4 s0v = sr[0], s1v = sr[1];
                acc[r] = fmaf(h0v.x, wU[0], acc[r]); acc[r] = fmaf(s0v.x, wP[0], acc[r]);
                acc[r] = fmaf(h0v.y, wU[1], acc[r]); acc[r] = fmaf(s0v.y, wP[1], acc[r]);
                acc[r] = fmaf(h0v.z, wU[2], acc[r]); acc[r] = fmaf(s0v.z, wP[2], acc[r]);
                acc[r] = fmaf(h0v.w, wU[3], acc[r]); acc[r] = fmaf(s0v.w, wP[3], acc[r]);
                acc[r] = fmaf(h1v.x, wU[4], acc[r]); acc[r] = fmaf(s1v.x, wP[4], acc[r]);
                acc[r] = fmaf(h1v.y, wU[5], acc[r]); acc[r] = fmaf(s1v.y, wP[5], acc[r]);
                acc[r] = fmaf(h1v.z, wU[6], acc[r]); acc[r] = fmaf(s1v.z, wP[6], acc[r]);
                acc[r] = fmaf(h1v.w, wU[7], acc[r]); acc[r] = fmaf(s1v.w, wP[7], acc[r]);
            }
        }
        #pragma unroll
        for (int r = 0; r < 8; r++) {
            int grow = rb + r0 + r;
            if (grow < n) {
                u[(size_t)grow * 64 + lane] = acc[r];
                s += acc[r];
                q = fmaf(acc[r], acc[r], q);
            }
        }
    }
    rs[wid][lane] = s; rq[wid][lane] = q;
    __syncthreads();
    if (wid == 0) {
        float ts = rs[0][lane] + rs[1][lane] + rs[2][lane] + rs[3][lane];
        float tq = rq[0][lane] + rq[1][lane] + rq[2][lane] + rq[3][lane];
        atomicAdd(&usum[lane], ts);
        atomicAdd(&usq[lane], tq);
    }
}

// ---------- layer-4 BN + SiLU fused with pooling ----------
__global__ __launch_bounds__(256) void k_bn_pool(const float* __restrict__ u, const float* __restrict__ usum,
                                                 const float* __restrict__ usq, const float* __restrict__ g,
                                                 const float* __restrict__ be, const int* __restrict__ batch,
                                                 float* __restrict__ gsum, float* __restrict__ gcnt,
                                                 int n, float invN) {
    __shared__ float ssc[64], ssh[64];
    if (threadIdx.x < 64) {
        int j = threadIdx.x;
        float mean = usum[j] * invN;
        float var = usq[j] * invN - mean * mean;
        float inv = rsqrtf(var + 1e-5f);
        float sc = inv * g[j];
        ssc[j] = sc;
        ssh[j] = fmaf(-mean, sc, be[j]);
    }
    __syncthreads();
    int lane = threadIdx.x & 63;
    int gw = (blockIdx.x * 256 + threadIdx.x) >> 6;
    int nw = (gridDim.x * 256) >> 6;
    int per = (n + nw - 1) / nw;
    int start = gw * per;
    int end = start + per; if (end > n) end = n;
    if (start >= end) return;
    float sc = ssc[lane], sh = ssh[lane];
    int cur = batch[start];
    float acc = 0.0f, c = 0.0f;
    for (int i = start; i < end; i++) {
        int b = batch[i];
        if (b != cur) {
            atomicAdd(&gsum[(size_t)cur * 64 + lane], acc);
            if (lane == 0) atomicAdd(&gcnt[cur], c);
            cur = b; acc = 0.0f; c = 0.0f;
        }
        float y = fmaf(u[(size_t)i * 64 + lane], sc, sh);
        acc += silu_f(y);
        c += 1.0f;
    }
    atomicAdd(&gsum[(size_t)cur * 64 + lane], acc);
    if (lane == 0) atomicAdd(&gcnt[cur], c);
}

// ---------- output ----------
__global__ __launch_bounds__(256) void k_out(const float* __restrict__ gsum, const float* __restrict__ gcnt,
                                             const float* __restrict__ OW, const float* __restrict__ ob,
                                             float* __restrict__ out, int G) {
    __shared__ float sW[4096];
    for (int i = threadIdx.x; i < 4096; i += 256) sW[i] = OW[i];
    __syncthreads();
    int lane = threadIdx.x & 63;
    int gw = (blockIdx.x * 256 + threadIdx.x) >> 6;
    int nw = (gridDim.x * 256) >> 6;
    for (int g = gw; g < G; g += nw) {
        int gu = rfl(g);
        float c = gcnt[gu]; if (c < 1.0f) c = 1.0f;
        float ci = 1.0f / c;
        float acc = ob[lane];
        const float* gr = gsum + (size_t)gu * 64;
        #pragma unroll
        for (int k = 0; k < 64; k++) acc = fmaf(gr[k] * ci, sW[k * 64 + lane], acc);
        out[(size_t)gu * 64 + lane] = silu_f(acc);
    }
}

extern "C" void kernel_launch(void* const* d_in, const int* in_sizes, int n_in,
                              void* d_out, int out_size, void* d_ws, size_t ws_size,
                              hipStream_t stream) {
    const int N = NN, E = EE, G = GG, L = LL;
    const float* x         = (const float*)d_in[0];
    const float* edge_attr = (const float*)d_in[1];
    const int*   edge_index= (const int*)d_in[2];
    const int*   batch     = (const int*)d_in[3];
    const float* node_W    = (const float*)d_in[4];
    const float* node_b    = (const float*)d_in[5];
    const float* msg_W1    = (const float*)d_in[6];
    const float* msg_b1    = (const float*)d_in[7];
    const float* msg_g1    = (const float*)d_in[8];
    const float* msg_be1   = (const float*)d_in[9];
    const float* msg_W2    = (const float*)d_in[10];
    const float* msg_b2    = (const float*)d_in[11];
    const float* upd_W     = (const float*)d_in[12];
    const float* upd_b     = (const float*)d_in[13];
    const float* upd_g     = (const float*)d_in[14];
    const float* upd_be    = (const float*)d_in[15];
    const float* out_W     = (const float*)d_in[16];
    const float* out_b     = (const float*)d_in[17];
    float* out = (float*)d_out;

    char* ws = (char*)d_ws;
    size_t off = 0;
    auto alloc = [&](size_t b) { size_t o = off; off = (off + b + 255) & ~(size_t)255; return o; };
    float* h0   = (float*)(ws + alloc((size_t)N * 64 * 4));
    float* Hd   = (float*)(ws + alloc((size_t)N * 64 * 4));
    _Float16* Hs = (_Float16*)(ws + alloc((size_t)N * 64 * 2));
    float* sacc = (float*)(ws + alloc((size_t)N * 64 * 4));
    float* u    = (float*)(ws + alloc((size_t)N * 64 * 4));
    unsigned int* edata = (unsigned int*)(ws + alloc((size_t)E * 4));
    int* rowptr = (int*)  (ws + alloc((size_t)(N + 1) * 4));
    float* degf = (float*)(ws + alloc((size_t)N * 4));
    float* W2p  = (float*)(ws + alloc((size_t)L * 4096 * 4));
    float* b2p  = (float*)(ws + alloc((size_t)L * 64 * 4));
    size_t zero_begin = off;
    int*   fill = (int*)  (ws + alloc((size_t)N * 4));
    float* stats= (float*)(ws + alloc((size_t)L * 4 * 64 * 4));  // per layer: esum,esq,usum,usq
    float* gsum = (float*)(ws + alloc((size_t)(G * 64 + G) * 4));
    size_t zero_end = off;
    float* gcnt = gsum + (size_t)G * 64;

    hipMemsetAsync(ws + zero_begin, 0, zero_end - zero_begin, stream);

    // CSR build
    k_hist<<<(E + 255) / 256, 256, 0, stream>>>(edge_index, fill, E);
    k_scan<<<1, 1024, 0, stream>>>(fill, rowptr, degf, fill, N);
    k_scatter<<<(E + 255) / 256, 256, 0, stream>>>(edge_index, edge_attr, rowptr, fill, edata, E);

    // weight fold + node embedding
    k_fold<<<L, 256, 0, stream>>>(msg_W2, msg_b2, upd_W, W2p, b2p);
    const int TILES64 = (N + 63) / 64;   // 782
    const int TILES32 = (N + 31) / 32;   // 1563
    k_node_emb<<<TILES64, 256, 0, stream>>>(x, node_W, node_b, h0, N);

    for (int l = 0; l < L; l++) {
        const float* W1  = msg_W1 + (size_t)l * 129 * 64;
        const float* w1e = W1 + 128 * 64;
        float* esum = stats + (size_t)l * 256;
        float* esq  = esum + 64;
        float* usum = esum + 128;
        float* usq  = esum + 192;
        int lp = (l > 0) ? (l - 1) : 0;
        const float* src = (l == 0) ? h0 : u;
        int bn = (l == 0) ? 0 : 1;
        const float* psum = stats + (size_t)lp * 256 + 128;  // usum of prev layer
        const float* psq  = psum + 64;
        k_node_pre<<<TILES64, 256, 0, stream>>>(src, bn, psum, psq, upd_g + lp * 64, upd_be + lp * 64,
                                                1.0f / N, W1, msg_b1 + l * 64, Hd, Hs, N);
        k_edge_stats<<<2048, 256, 0, stream>>>(Hd, Hs, rowptr, edata, w1e, esum, esq, N);
        k_edge_agg<<<2048, 256, 0, stream>>>(Hd, Hs, rowptr, edata, w1e, esum, esq,
                                             msg_g1 + l * 64, msg_be1 + l * 64, degf, sacc, N, 1.0f / E);
        k_node_upd<<<TILES32, 256, 0, stream>>>(src, bn, psum, psq, upd_g + lp * 64, upd_be + lp * 64,
                                                1.0f / N, sacc, upd_W + (size_t)l * 8192,
                                                W2p + (size_t)l * 4096, b2p + (size_t)l * 64,
                                                upd_b + l * 64, rowptr, u, usum, usq, N);
    }

    k_bn_pool<<<256, 256, 0, stream>>>(u, stats + 4 * 256 + 128, stats + 4 * 256 + 192,
                                       upd_g + 4 * 64, upd_be + 4 * 64, batch, gsum, gcnt, N, 1.0f / N);
    k_out<<<64, 256, 0, stream>>>(gsum, gcnt, out_W, out_b, out, G);
}

// Round 10
// 1356.200 us; speedup vs baseline: 4.9477x; 4.9477x over previous
//
#include <hip/hip_runtime.h>
#include <hip/hip_bf16.h>

#define NN 50000
#define EE 1200000
#define GG 256
#define LL 5

// fast silu
__device__ __forceinline__ float silu_f(float x) {
    return x * __builtin_amdgcn_rcpf(1.0f + __expf(-x));
}
__device__ __forceinline__ int rfl(int x) { return __builtin_amdgcn_readfirstlane(x); }

// ---------- CSR build ----------
__global__ __launch_bounds__(256) void k_hist(const int* __restrict__ ei, int* __restrict__ fill, int E) {
    int e = blockIdx.x * 256 + threadIdx.x;
    if (e < E) atomicAdd(&fill[ei[E + e]], 1);
}

__global__ __launch_bounds__(1024) void k_scan(const int* __restrict__ cnt, int* __restrict__ rowptr,
                                               float* __restrict__ degf, int* __restrict__ fill, int n) {
    __shared__ int wsum[16];
    __shared__ int carry_s;
    int tid = threadIdx.x, lane = tid & 63, wid = tid >> 6;
    if (tid == 0) carry_s = 0;
    __syncthreads();
    for (int base = 0; base < n; base += 1024) {
        int i = base + tid;
        int v = (i < n) ? cnt[i] : 0;
        int x = v;
        #pragma unroll
        for (int off = 1; off < 64; off <<= 1) {
            int t = __shfl_up(x, off);
            if (lane >= off) x += t;
        }
        if (lane == 63) wsum[wid] = x;
        __syncthreads();
        if (wid == 0 && lane < 16) {
            int w = wsum[lane];
            #pragma unroll
            for (int off = 1; off < 16; off <<= 1) {
                int t = __shfl_up(w, off);
                if (lane >= off) w += t;
            }
            wsum[lane] = w;
        }
        __syncthreads();
        int waveoff = (wid == 0) ? 0 : wsum[wid - 1];
        int inc = x + waveoff;
        int c = carry_s;
        int chunk_total = wsum[15];
        __syncthreads();
        if (i < n) {
            rowptr[i + 1] = c + inc;
            degf[i] = (float)(v > 0 ? v : 1);
            fill[i] = 0;
        }
        if (tid == 0) {
            if (base == 0) rowptr[0] = 0;
            carry_s = c + chunk_total;
        }
        __syncthreads();
    }
}

// packed scatter: ONE 4B write per edge. v = (ea15 << 17) | src  (src < 2^17, ea in [0,1) -> 15-bit fixed)
__global__ __launch_bounds__(256) void k_scatter(const int* __restrict__ ei, const float* __restrict__ ea,
                                                 const int* __restrict__ rowptr, int* __restrict__ fill,
                                                 unsigned int* __restrict__ edata, int E) {
    int e = blockIdx.x * 256 + threadIdx.x;
    if (e < E) {
        int d = ei[E + e];
        int pos = atomicAdd(&fill[d], 1);
        int idx = rowptr[d] + pos;
        int ea15 = (int)(ea[e] * 32768.0f + 0.5f);
        if (ea15 > 32767) ea15 = 32767;
        edata[idx] = ((unsigned int)ea15 << 17) | (unsigned int)ei[e];
    }
}

// ---------- weight fold ----------
__global__ __launch_bounds__(256) void k_fold(const float* __restrict__ msg_W2, const float* __restrict__ msg_b2,
                                              const float* __restrict__ upd_W, float* __restrict__ W2p,
                                              float* __restrict__ b2p) {
    int l = blockIdx.x;
    const float* W2 = msg_W2 + (size_t)l * 4096;
    const float* U2 = upd_W + (size_t)l * 8192 + 4096;
    int lane = threadIdx.x & 63, wid = threadIdx.x >> 6;
    for (int ii = 0; ii < 16; ii++) {
        int i = rfl(wid * 16 + ii);
        float acc = 0.0f;
        for (int k = 0; k < 64; k++) acc = fmaf(W2[i * 64 + k], U2[k * 64 + lane], acc);
        W2p[(size_t)l * 4096 + i * 64 + lane] = acc;
    }
    if (wid == 0) {
        float acc = 0.0f;
        for (int k = 0; k < 64; k++) acc = fmaf(msg_b2[l * 64 + k], U2[k * 64 + lane], acc);
        b2p[l * 64 + lane] = acc;
    }
}

// ---------- node embedding ----------
__global__ __launch_bounds__(256) void k_node_emb(const float* __restrict__ x, const float* __restrict__ W,
                                                  const float* __restrict__ b, float* __restrict__ h, int n) {
    __shared__ float sW[92 * 64];
    for (int i = threadIdx.x; i < 92 * 64; i += 256) sW[i] = W[i];
    __syncthreads();
    int lane = threadIdx.x & 63;
    int gw = (blockIdx.x * 256 + threadIdx.x) >> 6;
    int nw = (gridDim.x * 256) >> 6;
    float bj = b[lane];
    int tiles = n >> 3;
    for (int t = gw; t < tiles; t += nw) {
        int rb = rfl(t << 3);
        float acc[8];
        #pragma unroll
        for (int r = 0; r < 8; r++) acc[r] = bj;
        for (int kb = 0; kb < 80; kb += 16) {
            float wv[16];
            #pragma unroll
            for (int t2 = 0; t2 < 16; t2++) wv[t2] = sW[(kb + t2) * 64 + lane];
            #pragma unroll
            for (int r = 0; r < 8; r++) {
                const float* xr = x + (size_t)(rb + r) * 92 + kb;
                #pragma unroll
                for (int t2 = 0; t2 < 16; t2++) acc[r] = fmaf(xr[t2], wv[t2], acc[r]);
            }
        }
        {
            float wv[12];
            #pragma unroll
            for (int t2 = 0; t2 < 12; t2++) wv[t2] = sW[(80 + t2) * 64 + lane];
            #pragma unroll
            for (int r = 0; r < 8; r++) {
                const float* xr = x + (size_t)(rb + r) * 92 + 80;
                #pragma unroll
                for (int t2 = 0; t2 < 12; t2++) acc[r] = fmaf(xr[t2], wv[t2], acc[r]);
            }
        }
        #pragma unroll
        for (int r = 0; r < 8; r++) h[(size_t)(rb + r) * 64 + lane] = acc[r];
    }
}

// ---------- per-layer: Hd = h@W1[0:64] + b1 (fp32) ; Hs = h@W1[64:128] (fp16) ----------
__global__ __launch_bounds__(256) void k_node_pre(const float* __restrict__ h, const float* __restrict__ W1,
                                                  const float* __restrict__ b1, float* __restrict__ Hd,
                                                  _Float16* __restrict__ Hs, int n) {
    __shared__ float sA[4096], sB[4096];
    for (int i = threadIdx.x; i < 4096; i += 256) { sA[i] = W1[i]; sB[i] = W1[4096 + i]; }
    __syncthreads();
    int lane = threadIdx.x & 63;
    int gw = (blockIdx.x * 256 + threadIdx.x) >> 6;
    int nw = (gridDim.x * 256) >> 6;
    float bj = b1[lane];
    int tiles = n >> 3;
    for (int t = gw; t < tiles; t += nw) {
        int rb = rfl(t << 3);
        float accA[8], accB[8];
        #pragma unroll
        for (int r = 0; r < 8; r++) { accA[r] = bj; accB[r] = 0.0f; }
        for (int kb = 0; kb < 64; kb += 16) {
            float wA[16], wB[16];
            #pragma unroll
            for (int t2 = 0; t2 < 16; t2++) { wA[t2] = sA[(kb + t2) * 64 + lane]; wB[t2] = sB[(kb + t2) * 64 + lane]; }
            #pragma unroll
            for (int r = 0; r < 8; r++) {
                const float* hr = h + (size_t)(rb + r) * 64 + kb;
                #pragma unroll
                for (int t2 = 0; t2 < 16; t2++) {
                    float hk = hr[t2];
                    accA[r] = fmaf(hk, wA[t2], accA[r]);
                    accB[r] = fmaf(hk, wB[t2], accB[r]);
                }
            }
        }
        #pragma unroll
        for (int r = 0; r < 8; r++) {
            Hd[(size_t)(rb + r) * 64 + lane] = accA[r];
            Hs[(size_t)(rb + r) * 64 + lane] = (_Float16)accB[r];
        }
    }
}

// ---------- edge pass 1: sum(z), sum(z^2); fp16 gathers, 4B packed edata ----------
__global__ __launch_bounds__(256) void k_edge_stats(const float* __restrict__ Hd, const _Float16* __restrict__ Hs,
                                                    const int* __restrict__ rowptr, const unsigned int* __restrict__ edata,
                                                    const float* __restrict__ w1e,
                                                    float* __restrict__ esum, float* __restrict__ esq, int n) {
    __shared__ float rs[4][64], rq[4][64];
    int wid = threadIdx.x >> 6, lane = threadIdx.x & 63;
    int gw = (blockIdx.x * 256 + threadIdx.x) >> 6;
    int nw = (gridDim.x * 256) >> 6;
    float wj = w1e[lane] * (1.0f / 32768.0f);
    float s = 0.0f, q = 0.0f;
    for (int node = gw; node < n; node += nw) {
        int nu = rfl(node);
        int e0 = rowptr[nu], e1 = rowptr[nu + 1];
        if (e0 == e1) continue;
        float hd = Hd[(size_t)nu * 64 + lane];
        int e = e0;
        for (; e + 8 <= e1; e += 8) {
            float hs[8], av[8];
            #pragma unroll
            for (int j = 0; j < 8; j++) {
                unsigned int p = edata[e + j];
                int sidx = rfl((int)(p & 0x1FFFFu));
                av[j] = (float)rfl((int)(p >> 17));
                hs[j] = (float)Hs[(size_t)sidx * 64 + lane];
            }
            #pragma unroll
            for (int j = 0; j < 8; j++) {
                float z = fmaf(av[j], wj, hd) + hs[j];
                s += z;
                q = fmaf(z, z, q);
            }
        }
        for (; e < e1; e++) {
            unsigned int p = edata[e];
            int sidx = rfl((int)(p & 0x1FFFFu));
            float a = (float)rfl((int)(p >> 17));
            float z = fmaf(a, wj, hd) + (float)Hs[(size_t)sidx * 64 + lane];
            s += z;
            q = fmaf(z, z, q);
        }
    }
    rs[wid][lane] = s; rq[wid][lane] = q;
    __syncthreads();
    if (wid == 0) {
        float ts = rs[0][lane] + rs[1][lane] + rs[2][lane] + rs[3][lane];
        float tq = rq[0][lane] + rq[1][lane] + rq[2][lane] + rq[3][lane];
        atomicAdd(&esum[lane], ts);
        atomicAdd(&esq[lane], tq);
    }
}

// ---------- edge pass 2: sacc = (sum_in silu(bn(z)))/deg; fp16 gathers ----------
__global__ __launch_bounds__(256) void k_edge_agg(const float* __restrict__ Hd, const _Float16* __restrict__ Hs,
                                                  const int* __restrict__ rowptr, const unsigned int* __restrict__ edata,
                                                  const float* __restrict__ w1e,
                                                  const float* __restrict__ esum, const float* __restrict__ esq,
                                                  const float* __restrict__ g1, const float* __restrict__ be1,
                                                  const float* __restrict__ degf, float* __restrict__ sacc,
                                                  int n, float invE) {
    int lane = threadIdx.x & 63;
    float mean = esum[lane] * invE;
    float var = esq[lane] * invE - mean * mean;
    float inv = rsqrtf(var + 1e-5f);
    float sc = inv * g1[lane];
    float sh = fmaf(-mean, sc, be1[lane]);
    float wj = w1e[lane] * (1.0f / 32768.0f);
    int gw = (blockIdx.x * 256 + threadIdx.x) >> 6;
    int nw = (gridDim.x * 256) >> 6;
    for (int node = gw; node < n; node += nw) {
        int nu = rfl(node);
        int e0 = rowptr[nu], e1 = rowptr[nu + 1];
        float acc = 0.0f;
        float hd = Hd[(size_t)nu * 64 + lane];
        int e = e0;
        for (; e + 8 <= e1; e += 8) {
            float hs[8], av[8];
            #pragma unroll
            for (int j = 0; j < 8; j++) {
                unsigned int p = edata[e + j];
                int sidx = rfl((int)(p & 0x1FFFFu));
                av[j] = (float)rfl((int)(p >> 17));
                hs[j] = (float)Hs[(size_t)sidx * 64 + lane];
            }
            #pragma unroll
            for (int j = 0; j < 8; j++) {
                float z = fmaf(av[j], wj, hd) + hs[j];
                acc += silu_f(fmaf(z, sc, sh));
            }
        }
        for (; e < e1; e++) {
            unsigned int p = edata[e];
            int sidx = rfl((int)(p & 0x1FFFFu));
            float a = (float)rfl((int)(p >> 17));
            float z = fmaf(a, wj, hd) + (float)Hs[(size_t)sidx * 64 + lane];
            acc += silu_f(fmaf(z, sc, sh));
        }
        sacc[(size_t)nu * 64 + lane] = acc / degf[nu];
    }
}

// ---------- node update: u = h@U1 + sacc@W2p + gate*b2p + ub ; stats(u) ----------
__global__ __launch_bounds__(256) void k_node_upd(const float* __restrict__ h, const float* __restrict__ sacc,
                                                  const float* __restrict__ U1, const float* __restrict__ W2p,
                                                  const float* __restrict__ b2p, const float* __restrict__ ub,
                                                  const int* __restrict__ rowptr, float* __restrict__ u,
                                                  float* __restrict__ usum, float* __restrict__ usq, int n) {
    __shared__ float sU[4096], sP[4096];
    __shared__ float rs[4][64], rq[4][64];
    for (int i = threadIdx.x; i < 4096; i += 256) { sU[i] = U1[i]; sP[i] = W2p[i]; }
    __syncthreads();
    int wid = threadIdx.x >> 6, lane = threadIdx.x & 63;
    int gw = (blockIdx.x * 256 + threadIdx.x) >> 6;
    int nw = (gridDim.x * 256) >> 6;
    float b2j = b2p[lane], ubj = ub[lane];
    float s = 0.0f, q = 0.0f;
    int tiles = n >> 3;
    for (int t = gw; t < tiles; t += nw) {
        int rb = rfl(t << 3);
        float acc[8];
        #pragma unroll
        for (int r = 0; r < 8; r++) {
            int c0 = rowptr[rb + r], c1 = rowptr[rb + r + 1];
            acc[r] = ubj + (c1 > c0 ? b2j : 0.0f);
        }
        for (int kb = 0; kb < 64; kb += 16) {
            float wU[16], wP[16];
            #pragma unroll
            for (int t2 = 0; t2 < 16; t2++) { wU[t2] = sU[(kb + t2) * 64 + lane]; wP[t2] = sP[(kb + t2) * 64 + lane]; }
            #pragma unroll
            for (int r = 0; r < 8; r++) {
                const float* hr = h + (size_t)(rb + r) * 64 + kb;
                const float* sr = sacc + (size_t)(rb + r) * 64 + kb;
                #pragma unroll
                for (int t2 = 0; t2 < 16; t2++) {
                    acc[r] = fmaf(hr[t2], wU[t2], acc[r]);
                    acc[r] = fmaf(sr[t2], wP[t2], acc[r]);
                }
            }
        }
        #pragma unroll
        for (int r = 0; r < 8; r++) {
            u[(size_t)(rb + r) * 64 + lane] = acc[r];
            s += acc[r];
            q = fmaf(acc[r], acc[r], q);
        }
    }
    rs[wid][lane] = s; rq[wid][lane] = q;
    __syncthreads();
    if (wid == 0) {
        float ts = rs[0][lane] + rs[1][lane] + rs[2][lane] + rs[3][lane];
        float tq = rq[0][lane] + rq[1][lane] + rq[2][lane] + rq[3][lane];
        atomicAdd(&usum[lane], ts);
        atomicAdd(&usq[lane], tq);
    }
}

// ---------- node BN + SiLU (layers 0..3) ----------
__global__ __launch_bounds__(256) void k_node_bn(const float* __restrict__ u, const float* __restrict__ usum,
                                                 const float* __restrict__ usq, const float* __restrict__ g,
                                                 const float* __restrict__ be, float* __restrict__ h,
                                                 int n, float invN) {
    __shared__ float ssc[64], ssh[64];
    if (threadIdx.x < 64) {
        int j = threadIdx.x;
        float mean = usum[j] * invN;
        float var = usq[j] * invN - mean * mean;
        float inv = rsqrtf(var + 1e-5f);
        float sc = inv * g[j];
        ssc[j] = sc;
        ssh[j] = fmaf(-mean, sc, be[j]);
    }
    __syncthreads();
    int total = n * 64;
    for (int i = blockIdx.x * 256 + threadIdx.x; i < total; i += gridDim.x * 256) {
        int j = i & 63;
        float y = fmaf(u[i], ssc[j], ssh[j]);
        h[i] = silu_f(y);
    }
}

// ---------- layer-4 BN + SiLU fused with pooling ----------
__global__ __launch_bounds__(256) void k_bn_pool(const float* __restrict__ u, const float* __restrict__ usum,
                                                 const float* __restrict__ usq, const float* __restrict__ g,
                                                 const float* __restrict__ be, const int* __restrict__ batch,
                                                 float* __restrict__ gsum, float* __restrict__ gcnt,
                                                 int n, float invN) {
    __shared__ float ssc[64], ssh[64];
    if (threadIdx.x < 64) {
        int j = threadIdx.x;
        float mean = usum[j] * invN;
        float var = usq[j] * invN - mean * mean;
        float inv = rsqrtf(var + 1e-5f);
        float sc = inv * g[j];
        ssc[j] = sc;
        ssh[j] = fmaf(-mean, sc, be[j]);
    }
    __syncthreads();
    int lane = threadIdx.x & 63;
    int gw = (blockIdx.x * 256 + threadIdx.x) >> 6;
    int nw = (gridDim.x * 256) >> 6;
    int per = (n + nw - 1) / nw;
    int start = gw * per;
    int end = start + per; if (end > n) end = n;
    if (start >= end) return;
    float sc = ssc[lane], sh = ssh[lane];
    int cur = batch[start];
    float acc = 0.0f, c = 0.0f;
    for (int i = start; i < end; i++) {
        int b = batch[i];
        if (b != cur) {
            atomicAdd(&gsum[(size_t)cur * 64 + lane], acc);
            if (lane == 0) atomicAdd(&gcnt[cur], c);
            cur = b; acc = 0.0f; c = 0.0f;
        }
        float y = fmaf(u[(size_t)i * 64 + lane], sc, sh);
        acc += silu_f(y);
        c += 1.0f;
    }
    atomicAdd(&gsum[(size_t)cur * 64 + lane], acc);
    if (lane == 0) atomicAdd(&gcnt[cur], c);
}

// ---------- output ----------
__global__ __launch_bounds__(256) void k_out(const float* __restrict__ gsum, const float* __restrict__ gcnt,
                                             const float* __restrict__ OW, const float* __restrict__ ob,
                                             float* __restrict__ out, int G) {
    __shared__ float sW[4096];
    for (int i = threadIdx.x; i < 4096; i += 256) sW[i] = OW[i];
    __syncthreads();
    int lane = threadIdx.x & 63;
    int gw = (blockIdx.x * 256 + threadIdx.x) >> 6;
    int nw = (gridDim.x * 256) >> 6;
    for (int g = gw; g < G; g += nw) {
        int gu = rfl(g);
        float c = gcnt[gu]; if (c < 1.0f) c = 1.0f;
        float ci = 1.0f / c;
        float acc = ob[lane];
        const float* gr = gsum + (size_t)gu * 64;
        #pragma unroll
        for (int k = 0; k < 64; k++) acc = fmaf(gr[k] * ci, sW[k * 64 + lane], acc);
        out[(size_t)gu * 64 + lane] = silu_f(acc);
    }
}

extern "C" void kernel_launch(void* const* d_in, const int* in_sizes, int n_in,
                              void* d_out, int out_size, void* d_ws, size_t ws_size,
                              hipStream_t stream) {
    const int N = NN, E = EE, G = GG, L = LL;
    const float* x         = (const float*)d_in[0];
    const float* edge_attr = (const float*)d_in[1];
    const int*   edge_index= (const int*)d_in[2];
    const int*   batch     = (const int*)d_in[3];
    const float* node_W    = (const float*)d_in[4];
    const float* node_b    = (const float*)d_in[5];
    const float* msg_W1    = (const float*)d_in[6];
    const float* msg_b1    = (const float*)d_in[7];
    const float* msg_g1    = (const float*)d_in[8];
    const float* msg_be1   = (const float*)d_in[9];
    const float* msg_W2    = (const float*)d_in[10];
    const float* msg_b2    = (const float*)d_in[11];
    const float* upd_W     = (const float*)d_in[12];
    const float* upd_b     = (const float*)d_in[13];
    const float* upd_g     = (const float*)d_in[14];
    const float* upd_be    = (const float*)d_in[15];
    const float* out_W     = (const float*)d_in[16];
    const float* out_b     = (const float*)d_in[17];
    float* out = (float*)d_out;

    char* ws = (char*)d_ws;
    size_t off = 0;
    auto alloc = [&](size_t b) { size_t o = off; off = (off + b + 255) & ~(size_t)255; return o; };
    float* h    = (float*)(ws + alloc((size_t)N * 64 * 4));
    float* Hd   = (float*)(ws + alloc((size_t)N * 64 * 4));   // reused as u
    _Float16* Hs = (_Float16*)(ws + alloc((size_t)N * 64 * 2));
    float* sacc = (float*)(ws + alloc((size_t)N * 64 * 4));
    unsigned int* edata = (unsigned int*)(ws + alloc((size_t)E * 4));
    int* rowptr = (int*)  (ws + alloc((size_t)(N + 1) * 4));
    float* degf = (float*)(ws + alloc((size_t)N * 4));
    float* W2p  = (float*)(ws + alloc((size_t)L * 4096 * 4));
    float* b2p  = (float*)(ws + alloc((size_t)L * 64 * 4));
    size_t zero_begin = off;
    int*   fill = (int*)  (ws + alloc((size_t)N * 4));
    float* stats= (float*)(ws + alloc((size_t)L * 4 * 64 * 4));
    float* gsum = (float*)(ws + alloc((size_t)(G * 64 + G) * 4));
    size_t zero_end = off;
    float* gcnt = gsum + (size_t)G * 64;
    float* u = Hd;

    hipMemsetAsync(ws + zero_begin, 0, zero_end - zero_begin, stream);

    // CSR build
    k_hist<<<(E + 255) / 256, 256, 0, stream>>>(edge_index, fill, E);
    k_scan<<<1, 1024, 0, stream>>>(fill, rowptr, degf, fill, N);
    k_scatter<<<(E + 255) / 256, 256, 0, stream>>>(edge_index, edge_attr, rowptr, fill, edata, E);

    // weight fold + node embedding
    k_fold<<<L, 256, 0, stream>>>(msg_W2, msg_b2, upd_W, W2p, b2p);
    k_node_emb<<<1024, 256, 0, stream>>>(x, node_W, node_b, h, N);

    for (int l = 0; l < L; l++) {
        const float* W1  = msg_W1 + (size_t)l * 129 * 64;
        const float* w1e = W1 + 128 * 64;
        float* esum = stats + (size_t)l * 256;
        float* esq  = esum + 64;
        float* usum = esum + 128;
        float* usq  = esum + 192;
        k_node_pre<<<1024, 256, 0, stream>>>(h, W1, msg_b1 + l * 64, Hd, Hs, N);
        k_edge_stats<<<2048, 256, 0, stream>>>(Hd, Hs, rowptr, edata, w1e, esum, esq, N);
        k_edge_agg<<<2048, 256, 0, stream>>>(Hd, Hs, rowptr, edata, w1e, esum, esq,
                                             msg_g1 + l * 64, msg_be1 + l * 64, degf, sacc, N, 1.0f / E);
        k_node_upd<<<1024, 256, 0, stream>>>(h, sacc, upd_W + (size_t)l * 8192, W2p + (size_t)l * 4096,
                                             b2p + (size_t)l * 64, upd_b + l * 64, rowptr,
                                             u, usum, usq, N);
        if (l < L - 1) {
            k_node_bn<<<2048, 256, 0, stream>>>(u, usum, usq, upd_g + l * 64, upd_be + l * 64, h, N, 1.0f / N);
        } else {
            k_bn_pool<<<256, 256, 0, stream>>>(u, usum, usq, upd_g + l * 64, upd_be + l * 64,
                                               batch, gsum, gcnt, N, 1.0f / N);
        }
    }

    k_out<<<64, 256, 0, stream>>>(gsum, gcnt, out_W, out_b, out, G);
}